// Round 4
// baseline (550.796 us; speedup 1.0000x reference)
//
#include <hip/hip_runtime.h>
#include <stdint.h>

// Llama attention block, bf16 MFMA pipeline.
// B=2 S=2048 D=2048 NH=16 NKV=4 HD=128
#define B_    2
#define S_    2048
#define D_    2048
#define NH_   16
#define NKV_  4
#define HD_   128
#define M_    (B_*S_)     // 4096 rows
#define NQKV_ 3072        // NH*HD + 2*NKV*HD

typedef __bf16 bf16x8 __attribute__((ext_vector_type(8)));
typedef float  f32x4  __attribute__((ext_vector_type(4)));

__device__ __forceinline__ unsigned short f2bf(float f) {
    unsigned int u = __float_as_uint(f);
    u += 0x7fffu + ((u >> 16) & 1u);   // round-to-nearest-even
    return (unsigned short)(u >> 16);
}

// async global->LDS, 16B per lane; LDS dest = wave-uniform base + lane*16
__device__ __forceinline__ void async_cp16(const unsigned short* g, unsigned short* l) {
    __builtin_amdgcn_global_load_lds((const __attribute__((address_space(1))) void*)g,
                                     (__attribute__((address_space(3))) void*)l, 16, 0, 0);
}

// ---- cast x (fp32) -> bf16, 4 elems/thread ----
__global__ void cast_x(const float* __restrict__ x, unsigned short* __restrict__ xb) {
    int idx = blockIdx.x * 256 + threadIdx.x;
    float4 v = ((const float4*)x)[idx];
    unsigned int lo = (unsigned int)f2bf(v.x) | ((unsigned int)f2bf(v.y) << 16);
    unsigned int hi = (unsigned int)f2bf(v.z) | ((unsigned int)f2bf(v.w) << 16);
    ((uint2*)xb)[idx] = make_uint2(lo, hi);
}

// ---- transpose fp32 [2048][ncols] -> bf16 [ncols][2048] (B^T layout for GEMM) ----
__global__ void transpose_cast(const float* __restrict__ src,
                               unsigned short* __restrict__ dst, int ncols) {
    __shared__ float tile[32][33];
    int tx = threadIdx.x, ty = threadIdx.y;
    int n0 = blockIdx.x * 32, k0 = blockIdx.y * 32;
#pragma unroll
    for (int i = 0; i < 4; i++) {
        int k = k0 + ty + i * 8;
        tile[ty + i * 8][tx] = src[(long)k * ncols + n0 + tx];
    }
    __syncthreads();
#pragma unroll
    for (int i = 0; i < 4; i++) {
        int n = n0 + ty + i * 8;
        dst[(long)n * 2048 + k0 + tx] = f2bf(tile[tx][ty + i * 8]);
    }
}

// ---- RoPE cos/sin table: ctab[s*64+i] = {cos(s*invf_i), sin(s*invf_i)} ----
__global__ void rope_tables(float2* __restrict__ ctab) {
    int gid = blockIdx.x * 256 + threadIdx.x;   // 2048*64 entries
    int s = gid >> 6, i = gid & 63;
    float inv = exp2f(-(float)i * 0.20762050593046014f);  // 10000^(-i/64)
    float ang = (float)s * inv;
    float sn, cs; sincosf(ang, &sn, &cs);
    ctab[gid] = make_float2(cs, sn);
}

// ---- GEMM QKV (m97 structure, XCD-swizzled) with fused RoPE epilogue ----
// C would be [4096][3072]; instead: cols<2048 -> rope -> Qr bf16 [B][NH][S][128],
// cols 2048..2559 -> rope -> Kr bf16 [B][NKV][S][128], cols>=2560 -> Vrow bf16 [4096][512].
__global__ __launch_bounds__(256) void gemm_qkv(const unsigned short* __restrict__ A,
                                                const unsigned short* __restrict__ Bt,
                                                const float2* __restrict__ ctab,
                                                unsigned short* __restrict__ Qr,
                                                unsigned short* __restrict__ Kr,
                                                unsigned short* __restrict__ Vrow) {
    __shared__ unsigned short As[128 * 32];
    __shared__ unsigned short Bs[128 * 32];
    const int K = D_, N = NQKV_;
    // XCD swizzle: bid%8 = XCD (round-robin heuristic); each XCD owns 3 bx strips
    const int bid = blockIdx.x;
    const int xcd = bid & 7, ii = bid >> 3;
    const int bx = xcd * 3 + (ii % 3);
    const int by = ii / 3;
    const int tid  = threadIdx.x;
    const int lane = tid & 63, wid = tid >> 6;
    const int quad = lane >> 4, l16 = lane & 15;
    const int wm = wid >> 1, wn = wid & 1;
    const int m0 = by * 128, n0 = bx * 128;
    f32x4 acc[4][4] = {};

    for (int k0 = 0; k0 < K; k0 += 32) {
        __syncthreads();
#pragma unroll
        for (int i = 0; i < 2; i++) {
            int gbase = (wid * 2 + i) * 64;
            int g = gbase + lane;
            int row = g >> 2, c = (g & 3) * 8;
            async_cp16(&A[(long)(m0 + row) * K + k0 + c], &As[gbase * 8]);
            async_cp16(&Bt[(long)(n0 + row) * K + k0 + c], &Bs[gbase * 8]);
        }
        __syncthreads();
        bf16x8 af[4], bfr[4];
#pragma unroll
        for (int mt = 0; mt < 4; mt++)
            af[mt] = *(const bf16x8*)&As[(wm * 64 + mt * 16 + l16) * 32 + quad * 8];
#pragma unroll
        for (int nt = 0; nt < 4; nt++)
            bfr[nt] = *(const bf16x8*)&Bs[(wn * 64 + nt * 16 + l16) * 32 + quad * 8];
#pragma unroll
        for (int mt = 0; mt < 4; mt++)
#pragma unroll
            for (int nt = 0; nt < 4; nt++)
                acc[mt][nt] = __builtin_amdgcn_mfma_f32_16x16x32_bf16(af[mt], bfr[nt], acc[mt][nt], 0, 0, 0);
    }

    // ---- fused epilogue ----
    if (bx < 20) {
        // Q (bx<16) or K (16<=bx<20): RoPE via adjacent-lane pair exchange.
#pragma unroll
        for (int mt = 0; mt < 4; mt++)
#pragma unroll
            for (int nt = 0; nt < 4; nt++)
#pragma unroll
                for (int r = 0; r < 4; r++) {
                    int row = m0 + wm * 64 + mt * 16 + quad * 4 + r;
                    int s = row & 2047, b = row >> 11;
                    int col = n0 + wn * 64 + nt * 16 + l16;
                    int d = col & 127;
                    float2 cs = ctab[s * 64 + (d >> 1)];
                    float own = acc[mt][nt][r];
                    float other = __shfl_xor(own, 1);
                    float val = (d & 1) ? (other * cs.y + own * cs.x)
                                        : (own * cs.x - other * cs.y);
                    if (col < 2048) {
                        int h = col >> 7;
                        Qr[(((long)(b * 16 + h) * 2048 + s) * 128) + d] = f2bf(val);
                    } else {
                        int kvh = (col - 2048) >> 7;
                        Kr[(((long)(b * 4 + kvh) * 2048 + s) * 128) + d] = f2bf(val);
                    }
                }
    } else {
        // V: plain bf16 to row-major staging [4096][512]
#pragma unroll
        for (int mt = 0; mt < 4; mt++)
#pragma unroll
            for (int nt = 0; nt < 4; nt++)
#pragma unroll
                for (int r = 0; r < 4; r++) {
                    int row = m0 + wm * 64 + mt * 16 + quad * 4 + r;
                    int col = n0 + wn * 64 + nt * 16 + l16;
                    Vrow[(long)row * 512 + (col - 2560)] = f2bf(acc[mt][nt][r]);
                }
    }
}

// ---- GEMM (m97 structure, XCD-swizzled): C[M][N] fp32 = A @ Bt ----
__global__ __launch_bounds__(256) void gemm_bt(const unsigned short* __restrict__ A,
                                               const unsigned short* __restrict__ Bt,
                                               float* __restrict__ C, int N, int K,
                                               int nbxl) {
    __shared__ unsigned short As[128 * 32];
    __shared__ unsigned short Bs[128 * 32];
    const int bid = blockIdx.x;
    const int xcd = bid & 7, ii = bid >> 3;
    const int bx = xcd * nbxl + (ii % nbxl);
    const int by = ii / nbxl;
    const int tid  = threadIdx.x;
    const int lane = tid & 63, wid = tid >> 6;
    const int quad = lane >> 4, l16 = lane & 15;
    const int wm = wid >> 1, wn = wid & 1;
    const int m0 = by * 128, n0 = bx * 128;
    f32x4 acc[4][4] = {};

    for (int k0 = 0; k0 < K; k0 += 32) {
        __syncthreads();
#pragma unroll
        for (int i = 0; i < 2; i++) {
            int gbase = (wid * 2 + i) * 64;
            int g = gbase + lane;
            int row = g >> 2, c = (g & 3) * 8;
            async_cp16(&A[(long)(m0 + row) * K + k0 + c], &As[gbase * 8]);
            async_cp16(&Bt[(long)(n0 + row) * K + k0 + c], &Bs[gbase * 8]);
        }
        __syncthreads();
        bf16x8 af[4], bfr[4];
#pragma unroll
        for (int mt = 0; mt < 4; mt++)
            af[mt] = *(const bf16x8*)&As[(wm * 64 + mt * 16 + l16) * 32 + quad * 8];
#pragma unroll
        for (int nt = 0; nt < 4; nt++)
            bfr[nt] = *(const bf16x8*)&Bs[(wn * 64 + nt * 16 + l16) * 32 + quad * 8];
#pragma unroll
        for (int mt = 0; mt < 4; mt++)
#pragma unroll
            for (int nt = 0; nt < 4; nt++)
                acc[mt][nt] = __builtin_amdgcn_mfma_f32_16x16x32_bf16(af[mt], bfr[nt], acc[mt][nt], 0, 0, 0);
    }
#pragma unroll
    for (int mt = 0; mt < 4; mt++)
#pragma unroll
        for (int nt = 0; nt < 4; nt++)
#pragma unroll
            for (int r = 0; r < 4; r++) {
                long row = m0 + wm * 64 + mt * 16 + quad * 4 + r;
                long col = n0 + wn * 64 + nt * 16 + l16;
                C[row * N + col] = acc[mt][nt][r];
            }
}

// ---- V transpose (bf16): Vrow [4096][512] -> Vt [B][NKV][HD][S] ----
__global__ void v_trans_bf(const unsigned short* __restrict__ Vrow,
                           unsigned short* __restrict__ Vt) {
    __shared__ unsigned short tile[32][34];
    int tx = threadIdx.x, ty = threadIdx.y;
    int s0 = blockIdx.x * 32, d0 = blockIdx.y * 32;
    int bz = blockIdx.z;                       // b*NKV + kvh
    int b = bz >> 2, kvh = bz & 3;
#pragma unroll
    for (int i = 0; i < 4; i++) {
        int s = s0 + ty + i * 8;
        tile[ty + i * 8][tx] = Vrow[(long)(b * 2048 + s) * 512 + kvh * 128 + d0 + tx];
    }
    __syncthreads();
#pragma unroll
    for (int i = 0; i < 4; i++) {
        int d = d0 + ty + i * 8;
        Vt[((long)bz * 128 + d) * 2048 + s0 + tx] = tile[tx][ty + i * 8];
    }
}

// ---- Flash attention: causal, GQA. LDS-staged K/V, 2 barriers/iter,
// wave-private Ps. LPT grid: 32 variable-work strips, heavy dispatched first;
// grid = 1024 blocks (all resident, ~3 blocks/CU by LDS).
__global__ __launch_bounds__(256) void attn_fwd(const unsigned short* __restrict__ Qr,
                                                const unsigned short* __restrict__ Kr,
                                                const unsigned short* __restrict__ Vt,
                                                unsigned short* __restrict__ O) {
    __shared__ unsigned short Ks[64][136];    // kv x hd (+8 pad)
    __shared__ unsigned short Vs[128][72];    // hd x kv (+8 pad)
    __shared__ unsigned short Ps[4][16][72];  // per-wave P (wave-private)
    const int tid  = threadIdx.x;
    const int lane = tid & 63, wid = tid >> 6;
    const int quad = lane >> 4, l16 = lane & 15;
    const int qt = 31 - blockIdx.x;           // heavy strips first (LPT)
    const int h = blockIdx.y, b = blockIdx.z;
    const int kvh = h >> 2;                   // NH/NKV = 4
    const int qw = qt * 64 + wid * 16;        // this wave's 16 q rows
    const unsigned short* qp = Qr + (long)(b * NH_ + h) * S_ * HD_;
    const unsigned short* kp = Kr + (long)(b * NKV_ + kvh) * S_ * HD_;
    const unsigned short* vp = Vt + (long)(b * NKV_ + kvh) * HD_ * S_;
    const float sc2 = 0.08838834764831845f * 1.4426950408889634f;  // scale*log2e

    bf16x8 aq[4];
#pragma unroll
    for (int ks = 0; ks < 4; ks++)
        aq[ks] = *(const bf16x8*)&qp[(long)(qw + l16) * HD_ + ks * 32 + quad * 8];

    f32x4 o[8] = {};
    float mi[4], li[4];
#pragma unroll
    for (int r = 0; r < 4; r++) { mi[r] = -3.0e38f; li[r] = 0.f; }

    for (int kt = 0; kt <= qt; kt++) {
        const int kv0 = kt * 64;
        __syncthreads();
#pragma unroll
        for (int i = 0; i < 4; i++) {        // stage K tile: 64 x 128
            int idx = tid + i * 256;
            int row = idx >> 4, c = (idx & 15) * 8;
            *(uint4*)&Ks[row][c] = *(const uint4*)&kp[(long)(kv0 + row) * HD_ + c];
        }
#pragma unroll
        for (int i = 0; i < 4; i++) {        // stage V^T tile: 128 x 64
            int idx = tid + i * 256;
            int hd = idx >> 3, c = (idx & 7) * 8;
            *(uint4*)&Vs[hd][c] = *(const uint4*)&vp[(long)hd * S_ + kv0 + c];
        }
        __syncthreads();

        // S = Q K^T (16 x 64 per wave)
        f32x4 s[4] = {};
#pragma unroll
        for (int ks = 0; ks < 4; ks++)
#pragma unroll
            for (int nt = 0; nt < 4; nt++) {
                bf16x8 kb = *(const bf16x8*)&Ks[nt * 16 + l16][ks * 32 + quad * 8];
                s[nt] = __builtin_amdgcn_mfma_f32_16x16x32_bf16(aq[ks], kb, s[nt], 0, 0, 0);
            }

        // online softmax in exp2 domain
        float mt[4];
#pragma unroll
        for (int r = 0; r < 4; r++) mt[r] = -3.0e38f;
        if (kv0 + 63 > qw) {                 // diagonal tile: causal mask
#pragma unroll
            for (int nt = 0; nt < 4; nt++) {
                int kvp = kv0 + nt * 16 + l16;
#pragma unroll
                for (int r = 0; r < 4; r++) {
                    float sv = s[nt][r] * sc2;
                    sv = (kvp <= qw + quad * 4 + r) ? sv : -1.0e30f;
                    s[nt][r] = sv;
                    mt[r] = fmaxf(mt[r], sv);
                }
            }
        } else {
#pragma unroll
            for (int nt = 0; nt < 4; nt++)
#pragma unroll
                for (int r = 0; r < 4; r++) {
                    float sv = s[nt][r] * sc2;
                    s[nt][r] = sv;
                    mt[r] = fmaxf(mt[r], sv);
                }
        }
#pragma unroll
        for (int off = 1; off < 16; off <<= 1)
#pragma unroll
            for (int r = 0; r < 4; r++)
                mt[r] = fmaxf(mt[r], __shfl_xor(mt[r], off));
        float al[4], rs[4];
#pragma unroll
        for (int r = 0; r < 4; r++) {
            float mn = fmaxf(mi[r], mt[r]);
            al[r] = exp2f(mi[r] - mn);
            mi[r] = mn;
            rs[r] = 0.f;
        }
#pragma unroll
        for (int nt = 0; nt < 4; nt++)
#pragma unroll
            for (int r = 0; r < 4; r++) {
                float pv = exp2f(s[nt][r] - mi[r]);
                s[nt][r] = pv;
                rs[r] += pv;
            }
#pragma unroll
        for (int off = 1; off < 16; off <<= 1)
#pragma unroll
            for (int r = 0; r < 4; r++)
                rs[r] += __shfl_xor(rs[r], off);
#pragma unroll
        for (int r = 0; r < 4; r++) li[r] = li[r] * al[r] + rs[r];
#pragma unroll
        for (int t = 0; t < 8; t++)
#pragma unroll
            for (int r = 0; r < 4; r++) o[t][r] *= al[r];

        // P: C-layout -> wave-private LDS -> A-layout (no barrier)
#pragma unroll
        for (int nt = 0; nt < 4; nt++)
#pragma unroll
            for (int r = 0; r < 4; r++)
                Ps[wid][quad * 4 + r][nt * 16 + l16] = f2bf(s[nt][r]);

        // O += P V  (16 x 128 per wave)
#pragma unroll
        for (int ks2 = 0; ks2 < 2; ks2++) {
            bf16x8 pa = *(const bf16x8*)&Ps[wid][l16][ks2 * 32 + quad * 8];
#pragma unroll
            for (int vt = 0; vt < 8; vt++) {
                bf16x8 vb = *(const bf16x8*)&Vs[vt * 16 + l16][ks2 * 32 + quad * 8];
                o[vt] = __builtin_amdgcn_mfma_f32_16x16x32_bf16(pa, vb, o[vt], 0, 0, 0);
            }
        }
    }

    // epilogue: O/l -> attn buffer bf16 [b*S+s][h*128+hd]
#pragma unroll
    for (int r = 0; r < 4; r++) {
        float inv_l = 1.0f / li[r];
        int qpos = qw + quad * 4 + r;
#pragma unroll
        for (int vt = 0; vt < 8; vt++) {
            float val = o[vt][r] * inv_l;
            O[(long)(b * S_ + qpos) * 2048 + h * 128 + vt * 16 + l16] = f2bf(val);
        }
    }
}

extern "C" void kernel_launch(void* const* d_in, const int* in_sizes, int n_in,
                              void* d_out, int out_size, void* d_ws, size_t ws_size,
                              hipStream_t stream) {
    const float* x  = (const float*)d_in[0];
    // d_in[1] = mask: deterministic causal tril, applied analytically in attn_fwd.
    const float* Wq = (const float*)d_in[2];
    const float* Wk = (const float*)d_in[3];
    const float* Wv = (const float*)d_in[4];
    const float* Wo = (const float*)d_in[5];

    char* ws = (char*)d_ws;
    unsigned short* xb    = (unsigned short*)(ws);                 // 16,777,216 B
    unsigned short* Wqkvt = (unsigned short*)(ws + 16777216);      // 12,582,912 B
    unsigned short* Wot   = (unsigned short*)(ws + 29360128);      //  8,388,608 B
    float2*         ctab  = (float2*)        (ws + 37748736);      //  1,048,576 B
    unsigned short* Qr    = (unsigned short*)(ws + 38797312);      // 16,777,216 B
    unsigned short* Kr    = (unsigned short*)(ws + 55574528);      //  4,194,304 B
    unsigned short* Vrow  = (unsigned short*)(ws + 59768832);      //  4,194,304 B
    unsigned short* Vt    = (unsigned short*)(ws + 63963136);      //  4,194,304 B
    unsigned short* attn  = (unsigned short*)(ws + 68157440);      // 16,777,216 B -> 84,934,656 total

    cast_x<<<8192, 256, 0, stream>>>(x, xb);
    dim3 tb(32, 8);
    transpose_cast<<<dim3(64, 64), tb, 0, stream>>>(Wq, Wqkvt, 2048);
    transpose_cast<<<dim3(16, 64), tb, 0, stream>>>(Wk, Wqkvt + 2048 * 2048, 512);
    transpose_cast<<<dim3(16, 64), tb, 0, stream>>>(Wv, Wqkvt + 2560 * 2048, 512);
    transpose_cast<<<dim3(64, 64), tb, 0, stream>>>(Wo, Wot, 2048);
    rope_tables<<<512, 256, 0, stream>>>(ctab);

    // QKV GEMM with fused RoPE/V-split epilogue; 24x32 tiles, XCD-swizzled 1D grid
    gemm_qkv<<<24 * 32, 256, 0, stream>>>(xb, Wqkvt, ctab, Qr, Kr, Vrow);

    v_trans_bf<<<dim3(64, 4, 8), tb, 0, stream>>>(Vrow, Vt);

    attn_fwd<<<dim3(32, NH_, B_), 256, 0, stream>>>(Qr, Kr, Vt, attn);

    // out-proj: 16x32 tiles, XCD-swizzled (2 bx strips per XCD)
    gemm_bt<<<16 * 32, 256, 0, stream>>>(attn, Wot, (float*)d_out, D_, NH_ * HD_, 2);
}

// Round 5
// 381.649 us; speedup vs baseline: 1.4432x; 1.4432x over previous
//
#include <hip/hip_runtime.h>
#include <stdint.h>

// Llama attention block, bf16 MFMA pipeline.
// B=2 S=2048 D=2048 NH=16 NKV=4 HD=128
#define B_    2
#define S_    2048
#define D_    2048
#define NH_   16
#define NKV_  4
#define HD_   128
#define M_    (B_*S_)     // 4096 rows
#define NQKV_ 3072        // NH*HD + 2*NKV*HD

typedef __bf16 bf16x8 __attribute__((ext_vector_type(8)));
typedef float  f32x4  __attribute__((ext_vector_type(4)));

__device__ __forceinline__ unsigned short f2bf(float f) {
    unsigned int u = __float_as_uint(f);
    u += 0x7fffu + ((u >> 16) & 1u);   // round-to-nearest-even
    return (unsigned short)(u >> 16);
}

// async global->LDS, 16B per lane; LDS dest = wave-uniform base + lane*16
__device__ __forceinline__ void async_cp16(const unsigned short* g, unsigned short* l) {
    __builtin_amdgcn_global_load_lds((const __attribute__((address_space(1))) void*)g,
                                     (__attribute__((address_space(3))) void*)l, 16, 0, 0);
}

// ---- cast x (fp32) -> bf16, 4 elems/thread ----
__global__ void cast_x(const float* __restrict__ x, unsigned short* __restrict__ xb) {
    int idx = blockIdx.x * 256 + threadIdx.x;
    float4 v = ((const float4*)x)[idx];
    unsigned int lo = (unsigned int)f2bf(v.x) | ((unsigned int)f2bf(v.y) << 16);
    unsigned int hi = (unsigned int)f2bf(v.z) | ((unsigned int)f2bf(v.w) << 16);
    ((uint2*)xb)[idx] = make_uint2(lo, hi);
}

// ---- transpose fp32 [2048][ncols] -> bf16 [ncols][2048] (B^T layout for GEMM) ----
__global__ void transpose_cast(const float* __restrict__ src,
                               unsigned short* __restrict__ dst, int ncols) {
    __shared__ float tile[32][33];
    int tx = threadIdx.x, ty = threadIdx.y;
    int n0 = blockIdx.x * 32, k0 = blockIdx.y * 32;
#pragma unroll
    for (int i = 0; i < 4; i++) {
        int k = k0 + ty + i * 8;
        tile[ty + i * 8][tx] = src[(long)k * ncols + n0 + tx];
    }
    __syncthreads();
#pragma unroll
    for (int i = 0; i < 4; i++) {
        int n = n0 + ty + i * 8;
        dst[(long)n * 2048 + k0 + tx] = f2bf(tile[tx][ty + i * 8]);
    }
}

// ---- RoPE cos/sin table: ctab[s*64+i] = {cos(s*invf_i), sin(s*invf_i)} ----
__global__ void rope_tables(float2* __restrict__ ctab) {
    int gid = blockIdx.x * 256 + threadIdx.x;   // 2048*64 entries
    int s = gid >> 6, i = gid & 63;
    float inv = exp2f(-(float)i * 0.20762050593046014f);  // 10000^(-i/64)
    float ang = (float)s * inv;
    float sn, cs; sincosf(ang, &sn, &cs);
    ctab[gid] = make_float2(cs, sn);
}

// ---- GEMM QKV (m97 structure) with fused RoPE epilogue ----
// cols<2048 -> rope -> Qr bf16 [B][NH][S][128], cols 2048..2559 -> rope ->
// Kr bf16 [B][NKV][S][128], cols>=2560 -> Vrow bf16 [4096][512].
__global__ __launch_bounds__(256) void gemm_qkv(const unsigned short* __restrict__ A,
                                                const unsigned short* __restrict__ Bt,
                                                const float2* __restrict__ ctab,
                                                unsigned short* __restrict__ Qr,
                                                unsigned short* __restrict__ Kr,
                                                unsigned short* __restrict__ Vrow) {
    __shared__ unsigned short As[128 * 32];
    __shared__ unsigned short Bs[128 * 32];
    const int K = D_;
    const int bx = blockIdx.x, by = blockIdx.y;
    const int tid  = threadIdx.x;
    const int lane = tid & 63, wid = tid >> 6;
    const int quad = lane >> 4, l16 = lane & 15;
    const int wm = wid >> 1, wn = wid & 1;
    const int m0 = by * 128, n0 = bx * 128;
    f32x4 acc[4][4] = {};

    for (int k0 = 0; k0 < K; k0 += 32) {
        __syncthreads();
#pragma unroll
        for (int i = 0; i < 2; i++) {
            int gbase = (wid * 2 + i) * 64;
            int g = gbase + lane;
            int row = g >> 2, c = (g & 3) * 8;
            async_cp16(&A[(long)(m0 + row) * K + k0 + c], &As[gbase * 8]);
            async_cp16(&Bt[(long)(n0 + row) * K + k0 + c], &Bs[gbase * 8]);
        }
        __syncthreads();
        bf16x8 af[4], bfr[4];
#pragma unroll
        for (int mt = 0; mt < 4; mt++)
            af[mt] = *(const bf16x8*)&As[(wm * 64 + mt * 16 + l16) * 32 + quad * 8];
#pragma unroll
        for (int nt = 0; nt < 4; nt++)
            bfr[nt] = *(const bf16x8*)&Bs[(wn * 64 + nt * 16 + l16) * 32 + quad * 8];
#pragma unroll
        for (int mt = 0; mt < 4; mt++)
#pragma unroll
            for (int nt = 0; nt < 4; nt++)
                acc[mt][nt] = __builtin_amdgcn_mfma_f32_16x16x32_bf16(af[mt], bfr[nt], acc[mt][nt], 0, 0, 0);
    }

    // ---- fused epilogue ----
    if (bx < 20) {
        // Q (bx<16) or K (16<=bx<20): RoPE via adjacent-lane pair exchange.
#pragma unroll
        for (int mt = 0; mt < 4; mt++)
#pragma unroll
            for (int nt = 0; nt < 4; nt++)
#pragma unroll
                for (int r = 0; r < 4; r++) {
                    int row = m0 + wm * 64 + mt * 16 + quad * 4 + r;
                    int s = row & 2047, b = row >> 11;
                    int col = n0 + wn * 64 + nt * 16 + l16;
                    int d = col & 127;
                    float2 cs = ctab[s * 64 + (d >> 1)];
                    float own = acc[mt][nt][r];
                    float other = __shfl_xor(own, 1);
                    float val = (d & 1) ? (other * cs.y + own * cs.x)
                                        : (own * cs.x - other * cs.y);
                    if (col < 2048) {
                        int h = col >> 7;
                        Qr[(((long)(b * 16 + h) * 2048 + s) * 128) + d] = f2bf(val);
                    } else {
                        int kvh = (col - 2048) >> 7;
                        Kr[(((long)(b * 4 + kvh) * 2048 + s) * 128) + d] = f2bf(val);
                    }
                }
    } else {
        // V: plain bf16 to row-major staging [4096][512]
#pragma unroll
        for (int mt = 0; mt < 4; mt++)
#pragma unroll
            for (int nt = 0; nt < 4; nt++)
#pragma unroll
                for (int r = 0; r < 4; r++) {
                    int row = m0 + wm * 64 + mt * 16 + quad * 4 + r;
                    int col = n0 + wn * 64 + nt * 16 + l16;
                    Vrow[(long)row * 512 + (col - 2560)] = f2bf(acc[mt][nt][r]);
                }
    }
}

// ---- GEMM (m97 structure): C[M][N] fp32 = A @ Bt ----
__global__ __launch_bounds__(256) void gemm_bt(const unsigned short* __restrict__ A,
                                               const unsigned short* __restrict__ Bt,
                                               float* __restrict__ C, int N, int K) {
    __shared__ unsigned short As[128 * 32];
    __shared__ unsigned short Bs[128 * 32];
    const int bx = blockIdx.x, by = blockIdx.y;
    const int tid  = threadIdx.x;
    const int lane = tid & 63, wid = tid >> 6;
    const int quad = lane >> 4, l16 = lane & 15;
    const int wm = wid >> 1, wn = wid & 1;
    const int m0 = by * 128, n0 = bx * 128;
    f32x4 acc[4][4] = {};

    for (int k0 = 0; k0 < K; k0 += 32) {
        __syncthreads();
#pragma unroll
        for (int i = 0; i < 2; i++) {
            int gbase = (wid * 2 + i) * 64;
            int g = gbase + lane;
            int row = g >> 2, c = (g & 3) * 8;
            async_cp16(&A[(long)(m0 + row) * K + k0 + c], &As[gbase * 8]);
            async_cp16(&Bt[(long)(n0 + row) * K + k0 + c], &Bs[gbase * 8]);
        }
        __syncthreads();
        bf16x8 af[4], bfr[4];
#pragma unroll
        for (int mt = 0; mt < 4; mt++)
            af[mt] = *(const bf16x8*)&As[(wm * 64 + mt * 16 + l16) * 32 + quad * 8];
#pragma unroll
        for (int nt = 0; nt < 4; nt++)
            bfr[nt] = *(const bf16x8*)&Bs[(wn * 64 + nt * 16 + l16) * 32 + quad * 8];
#pragma unroll
        for (int mt = 0; mt < 4; mt++)
#pragma unroll
            for (int nt = 0; nt < 4; nt++)
                acc[mt][nt] = __builtin_amdgcn_mfma_f32_16x16x32_bf16(af[mt], bfr[nt], acc[mt][nt], 0, 0, 0);
    }
#pragma unroll
    for (int mt = 0; mt < 4; mt++)
#pragma unroll
        for (int nt = 0; nt < 4; nt++)
#pragma unroll
            for (int r = 0; r < 4; r++) {
                long row = m0 + wm * 64 + mt * 16 + quad * 4 + r;
                long col = n0 + wn * 64 + nt * 16 + l16;
                C[row * N + col] = acc[mt][nt][r];
            }
}

// ---- V transpose (bf16): Vrow [4096][512] -> Vt [B][NKV][HD][S] ----
__global__ void v_trans_bf(const unsigned short* __restrict__ Vrow,
                           unsigned short* __restrict__ Vt) {
    __shared__ unsigned short tile[32][34];
    int tx = threadIdx.x, ty = threadIdx.y;
    int s0 = blockIdx.x * 32, d0 = blockIdx.y * 32;
    int bz = blockIdx.z;                       // b*NKV + kvh
    int b = bz >> 2, kvh = bz & 3;
#pragma unroll
    for (int i = 0; i < 4; i++) {
        int s = s0 + ty + i * 8;
        tile[ty + i * 8][tx] = Vrow[(long)(b * 2048 + s) * 512 + kvh * 128 + d0 + tx];
    }
    __syncthreads();
#pragma unroll
    for (int i = 0; i < 4; i++) {
        int d = d0 + ty + i * 8;
        Vt[((long)bz * 128 + d) * 2048 + s0 + tx] = tile[tx][ty + i * 8];
    }
}

// ---- Flash attention: causal, GQA. LDS-staged K/V, 2 barriers/iter,
// wave-private Ps. Uniform work: block pid handles q-strips {31-pid, pid}
// sequentially -> exactly 33 kv-iters/block, grid 512 (proven R3 config;
// LPT/dispatch-order tricks measured useless - dispatch order is undefined).
// Row-sum via MFMA against all-ones B frag (replaces 16 shfl + 32 VALU/iter).
__global__ __launch_bounds__(256) void attn_fwd(const unsigned short* __restrict__ Qr,
                                                const unsigned short* __restrict__ Kr,
                                                const unsigned short* __restrict__ Vt,
                                                unsigned short* __restrict__ O) {
    __shared__ unsigned short Ks[64][136];    // kv x hd (+8 pad)
    __shared__ unsigned short Vs[128][72];    // hd x kv (+8 pad)
    __shared__ unsigned short Ps[4][16][72];  // per-wave P (wave-private)
    const int tid  = threadIdx.x;
    const int lane = tid & 63, wid = tid >> 6;
    const int quad = lane >> 4, l16 = lane & 15;
    const int pid = blockIdx.x, h = blockIdx.y, b = blockIdx.z;
    const int kvh = h >> 2;                   // NH/NKV = 4
    const unsigned short* qp = Qr + (long)(b * NH_ + h) * S_ * HD_;
    const unsigned short* kp = Kr + (long)(b * NKV_ + kvh) * S_ * HD_;
    const unsigned short* vp = Vt + (long)(b * NKV_ + kvh) * HD_ * S_;
    const float sc2 = 0.08838834764831845f * 1.4426950408889634f;  // scale*log2e

    bf16x8 ones;
#pragma unroll
    for (int i = 0; i < 8; i++) ones[i] = (__bf16)1.0f;

    for (int phase = 0; phase < 2; phase++) {
        const int qt = phase ? pid : 31 - pid;    // heavy strip first
        const int qw = qt * 64 + wid * 16;        // this wave's 16 q rows

        bf16x8 aq[4];
#pragma unroll
        for (int ks = 0; ks < 4; ks++)
            aq[ks] = *(const bf16x8*)&qp[(long)(qw + l16) * HD_ + ks * 32 + quad * 8];

        f32x4 o[8] = {};
        float mi[4], li[4];
#pragma unroll
        for (int r = 0; r < 4; r++) { mi[r] = -3.0e38f; li[r] = 0.f; }

        for (int kt = 0; kt <= qt; kt++) {
            const int kv0 = kt * 64;
            __syncthreads();
#pragma unroll
            for (int i = 0; i < 4; i++) {        // stage K tile: 64 x 128
                int idx = tid + i * 256;
                int row = idx >> 4, c = (idx & 15) * 8;
                *(uint4*)&Ks[row][c] = *(const uint4*)&kp[(long)(kv0 + row) * HD_ + c];
            }
#pragma unroll
            for (int i = 0; i < 4; i++) {        // stage V^T tile: 128 x 64
                int idx = tid + i * 256;
                int hd = idx >> 3, c = (idx & 7) * 8;
                *(uint4*)&Vs[hd][c] = *(const uint4*)&vp[(long)hd * S_ + kv0 + c];
            }
            __syncthreads();

            // S = Q K^T (16 x 64 per wave)
            f32x4 s[4] = {};
#pragma unroll
            for (int ks = 0; ks < 4; ks++)
#pragma unroll
                for (int nt = 0; nt < 4; nt++) {
                    bf16x8 kb = *(const bf16x8*)&Ks[nt * 16 + l16][ks * 32 + quad * 8];
                    s[nt] = __builtin_amdgcn_mfma_f32_16x16x32_bf16(aq[ks], kb, s[nt], 0, 0, 0);
                }

            // online softmax in exp2 domain (row max via shfl; sum via MFMA below)
            float mt[4];
#pragma unroll
            for (int r = 0; r < 4; r++) mt[r] = -3.0e38f;
            if (kv0 + 63 > qw) {                 // diagonal tile: causal mask
#pragma unroll
                for (int nt = 0; nt < 4; nt++) {
                    int kvp = kv0 + nt * 16 + l16;
#pragma unroll
                    for (int r = 0; r < 4; r++) {
                        float sv = s[nt][r] * sc2;
                        sv = (kvp <= qw + quad * 4 + r) ? sv : -1.0e30f;
                        s[nt][r] = sv;
                        mt[r] = fmaxf(mt[r], sv);
                    }
                }
            } else {
#pragma unroll
                for (int nt = 0; nt < 4; nt++)
#pragma unroll
                    for (int r = 0; r < 4; r++) {
                        float sv = s[nt][r] * sc2;
                        s[nt][r] = sv;
                        mt[r] = fmaxf(mt[r], sv);
                    }
            }
#pragma unroll
            for (int off = 1; off < 16; off <<= 1)
#pragma unroll
                for (int r = 0; r < 4; r++)
                    mt[r] = fmaxf(mt[r], __shfl_xor(mt[r], off));
            float al[4];
#pragma unroll
            for (int r = 0; r < 4; r++) {
                float mn = fmaxf(mi[r], mt[r]);
                al[r] = exp2f(mi[r] - mn);
                mi[r] = mn;
            }
#pragma unroll
            for (int nt = 0; nt < 4; nt++)
#pragma unroll
                for (int r = 0; r < 4; r++)
                    s[nt][r] = exp2f(s[nt][r] - mi[r]);
#pragma unroll
            for (int t = 0; t < 8; t++)
#pragma unroll
                for (int r = 0; r < 4; r++) o[t][r] *= al[r];

            // P: C-layout -> wave-private LDS -> A-layout (no barrier)
#pragma unroll
            for (int nt = 0; nt < 4; nt++)
#pragma unroll
                for (int r = 0; r < 4; r++)
                    Ps[wid][quad * 4 + r][nt * 16 + l16] = f2bf(s[nt][r]);

            // O += P V; row-sums of P via MFMA with all-ones B (layout-free)
            f32x4 sumf = {};
#pragma unroll
            for (int ks2 = 0; ks2 < 2; ks2++) {
                bf16x8 pa = *(const bf16x8*)&Ps[wid][l16][ks2 * 32 + quad * 8];
                sumf = __builtin_amdgcn_mfma_f32_16x16x32_bf16(pa, ones, sumf, 0, 0, 0);
#pragma unroll
                for (int vt = 0; vt < 8; vt++) {
                    bf16x8 vb = *(const bf16x8*)&Vs[vt * 16 + l16][ks2 * 32 + quad * 8];
                    o[vt] = __builtin_amdgcn_mfma_f32_16x16x32_bf16(pa, vb, o[vt], 0, 0, 0);
                }
            }
#pragma unroll
            for (int r = 0; r < 4; r++) li[r] = li[r] * al[r] + sumf[r];
        }

        // epilogue: O/l -> attn buffer bf16 [b*S+s][h*128+hd]
#pragma unroll
        for (int r = 0; r < 4; r++) {
            float inv_l = 1.0f / li[r];
            int qpos = qw + quad * 4 + r;
#pragma unroll
            for (int vt = 0; vt < 8; vt++) {
                float val = o[vt][r] * inv_l;
                O[(long)(b * S_ + qpos) * 2048 + h * 128 + vt * 16 + l16] = f2bf(val);
            }
        }
    }
}

extern "C" void kernel_launch(void* const* d_in, const int* in_sizes, int n_in,
                              void* d_out, int out_size, void* d_ws, size_t ws_size,
                              hipStream_t stream) {
    const float* x  = (const float*)d_in[0];
    // d_in[1] = mask: deterministic causal tril, applied analytically in attn_fwd.
    const float* Wq = (const float*)d_in[2];
    const float* Wk = (const float*)d_in[3];
    const float* Wv = (const float*)d_in[4];
    const float* Wo = (const float*)d_in[5];

    char* ws = (char*)d_ws;
    unsigned short* xb    = (unsigned short*)(ws);                 // 16,777,216 B
    unsigned short* Wqkvt = (unsigned short*)(ws + 16777216);      // 12,582,912 B
    unsigned short* Wot   = (unsigned short*)(ws + 29360128);      //  8,388,608 B
    float2*         ctab  = (float2*)        (ws + 37748736);      //  1,048,576 B
    unsigned short* Qr    = (unsigned short*)(ws + 38797312);      // 16,777,216 B
    unsigned short* Kr    = (unsigned short*)(ws + 55574528);      //  4,194,304 B
    unsigned short* Vrow  = (unsigned short*)(ws + 59768832);      //  4,194,304 B
    unsigned short* Vt    = (unsigned short*)(ws + 63963136);      //  4,194,304 B
    unsigned short* attn  = (unsigned short*)(ws + 68157440);      // 16,777,216 B

    cast_x<<<8192, 256, 0, stream>>>(x, xb);
    dim3 tb(32, 8);
    transpose_cast<<<dim3(64, 64), tb, 0, stream>>>(Wq, Wqkvt, 2048);
    transpose_cast<<<dim3(16, 64), tb, 0, stream>>>(Wk, Wqkvt + 2048 * 2048, 512);
    transpose_cast<<<dim3(16, 64), tb, 0, stream>>>(Wv, Wqkvt + 2560 * 2048, 512);
    transpose_cast<<<dim3(64, 64), tb, 0, stream>>>(Wo, Wot, 2048);
    rope_tables<<<512, 256, 0, stream>>>(ctab);

    // QKV GEMM with fused RoPE/V-split epilogue (plain 2D grid)
    gemm_qkv<<<dim3(24, 32), 256, 0, stream>>>(xb, Wqkvt, ctab, Qr, Kr, Vrow);

    v_trans_bf<<<dim3(64, 4, 8), tb, 0, stream>>>(Vrow, Vt);

    attn_fwd<<<dim3(16, NH_, B_), 256, 0, stream>>>(Qr, Kr, Vt, attn);

    gemm_bt<<<dim3(16, 32), 256, 0, stream>>>(attn, Wot, (float*)d_out, D_, NH_ * HD_);
}